// Round 1
// baseline (425.290 us; speedup 1.0000x reference)
//
#include <hip/hip_runtime.h>
#include <math.h>

#define NROWS 4194304
#define M4Q   (NROWS/4)
#define EPSV  1e-5f
#define NBLK  1024
#define NTHR  256
#define TOTT  (NBLK*NTHR)

// Stage numbering: 0:x  1:h1  2:z1  3:h2  4:z2  5:h3  6:z3  7:h4  8:z4
// Stats layout: stage s at stats + 32*s, 20 floats used (5 sums + 15 upper-tri prods)
// Lin layer L's input activation is exactly stage L.

struct FoldLDS { float A[5][5]; float c[5]; };

__device__ inline float4 mk4(float v){ return make_float4(v,v,v,v); }
__device__ inline float4 fma44(float a, const float4& b, const float4& c){
  return make_float4(fmaf(a,b.x,c.x), fmaf(a,b.y,c.y), fmaf(a,b.z,c.z), fmaf(a,b.w,c.w));
}
__device__ inline float4 relu4(const float4& a){
  return make_float4(fmaxf(a.x,0.f),fmaxf(a.y,0.f),fmaxf(a.z,0.f),fmaxf(a.w,0.f));
}

__device__ inline void acc_stats(const float4 z[5], float acc[20]){
  #pragma unroll
  for(int d=0; d<5; ++d) acc[d] += (z[d].x + z[d].y) + (z[d].z + z[d].w);
  int k = 5;
  #pragma unroll
  for(int d=0; d<5; ++d){
    #pragma unroll
    for(int e=d; e<5; ++e){
      acc[k] += z[d].x*z[e].x + z[d].y*z[e].y + z[d].z*z[e].z + z[d].w*z[e].w;
      ++k;
    }
  }
}

__device__ inline void reduce_atomic(float acc[20], float* dst){
  #pragma unroll
  for(int k=0;k<20;++k){
    float v = acc[k];
    #pragma unroll
    for(int m=32;m>=1;m>>=1) v += __shfl_xor(v, m);
    acc[k] = v;
  }
  __shared__ float red[(NTHR/64)*20];
  const int lane = threadIdx.x & 63, wv = threadIdx.x >> 6;
  if(lane==0){
    #pragma unroll
    for(int k=0;k<20;++k) red[wv*20+k] = acc[k];
  }
  __syncthreads();
  if(threadIdx.x < 20){
    float s = 0.f;
    #pragma unroll
    for(int w=0; w<NTHR/64; ++w) s += red[w*20 + threadIdx.x];
    atomicAdd(dst + threadIdx.x, s);
  }
}

// Fold BN(Lin(z)) into affine y = A z + c, given raw stats sums of z.
// Linear bias cancels inside BN (BN subtracts the mean), so it is not needed.
__device__ inline void fold_generic(const float* __restrict__ sums,
                                    const float* __restrict__ W,
                                    const float* __restrict__ g,
                                    const float* __restrict__ be,
                                    int c, float* Arow, float* cout){
  const float invN = 1.0f/(float)NROWS;
  float mu[5];
  #pragma unroll
  for(int d=0;d<5;++d) mu[d] = sums[d]*invN;
  float wr[5];
  #pragma unroll
  for(int d=0;d<5;++d) wr[d] = W[c*5+d];
  float m = 0.f, v = 0.f;
  #pragma unroll
  for(int d=0;d<5;++d){
    m += wr[d]*mu[d];
    #pragma unroll
    for(int e=0;e<5;++e){
      const int dd = d<e?d:e, ee = d<e?e:d;
      const float cov = sums[5 + dd*5+ee - (dd*(dd+1))/2]*invN - mu[d]*mu[e];
      v += wr[d]*wr[e]*cov;
    }
  }
  const float s = g[c] / sqrtf(v + EPSV);
  #pragma unroll
  for(int d=0;d<5;++d) Arow[d] = s*wr[d];
  *cout = be[c] - s*m;
}

__device__ inline void fold_layer(const float* sums, const float* W,
                                  const float* g, const float* be, FoldLDS* F){
  if(threadIdx.x < 5)
    fold_generic(sums, W, g, be, (int)threadIdx.x,
                 &F->A[threadIdx.x][0], &F->c[threadIdx.x]);
}

// ---------------- main (big-ws) path: SoA z-buffer in ws ----------------

__global__ __launch_bounds__(NTHR)
void k_transpose_stats(const float* __restrict__ x, float* __restrict__ zbuf,
                       float* __restrict__ stats){
  float acc[20];
  #pragma unroll
  for(int k=0;k<20;++k) acc[k]=0.f;
  const int gid = blockIdx.x*NTHR + threadIdx.x;
  for(int t=gid; t<M4Q; t+=TOTT){
    union { float4 v[5]; float f[20]; } u;
    const float4* xp = (const float4*)(x + (size_t)t*20);
    #pragma unroll
    for(int q=0;q<5;++q) u.v[q] = xp[q];
    float4 z[5];
    #pragma unroll
    for(int c=0;c<5;++c) z[c] = make_float4(u.f[c], u.f[5+c], u.f[10+c], u.f[15+c]);
    #pragma unroll
    for(int c=0;c<5;++c) ((float4*)(zbuf + (size_t)c*NROWS))[t] = z[c];
    acc_stats(z, acc);
  }
  reduce_atomic(acc, stats);
}

__global__ __launch_bounds__(NTHR)
void k_stats_h(const float* __restrict__ zbuf, float* __restrict__ stats,
               const float* __restrict__ lins_w, const float* __restrict__ bn_g,
               const float* __restrict__ bn_b, int blk){
  __shared__ FoldLDS F1;
  const int i = 2*blk;
  fold_layer(stats + 32*i, lins_w + 25*i, bn_g + 5*i, bn_b + 5*i, &F1);
  __syncthreads();
  float A1[5][5], c1[5];
  #pragma unroll
  for(int c=0;c<5;++c){
    c1[c] = F1.c[c];
    #pragma unroll
    for(int d=0;d<5;++d) A1[c][d] = F1.A[c][d];
  }
  float acc[20];
  #pragma unroll
  for(int k=0;k<20;++k) acc[k]=0.f;
  const int gid = blockIdx.x*NTHR + threadIdx.x;
  for(int t=gid; t<M4Q; t+=TOTT){
    float4 z[5], h[5];
    #pragma unroll
    for(int c=0;c<5;++c) z[c] = ((const float4*)(zbuf + (size_t)c*NROWS))[t];
    #pragma unroll
    for(int c=0;c<5;++c){
      float4 u = mk4(c1[c]);
      #pragma unroll
      for(int d=0;d<5;++d) u = fma44(A1[c][d], z[d], u);
      h[c] = relu4(u);
    }
    acc_stats(h, acc);
  }
  reduce_atomic(acc, stats + 32*(2*blk+1));
}

__global__ __launch_bounds__(NTHR)
void k_update_z(float* __restrict__ zbuf, float* __restrict__ stats,
                const float* __restrict__ lins_w, const float* __restrict__ bn_g,
                const float* __restrict__ bn_b, const float* __restrict__ skips_w,
                const float* __restrict__ skips_b, int blk){
  __shared__ FoldLDS F1, F2;
  const int i = 2*blk, j = 2*blk+1;
  fold_layer(stats + 32*i, lins_w + 25*i, bn_g + 5*i, bn_b + 5*i, &F1);
  fold_layer(stats + 32*j, lins_w + 25*j, bn_g + 5*j, bn_b + 5*j, &F2);
  __syncthreads();
  float A1[5][5], c1[5], A2[5][5], c2[5], SWr[25], SBr[5];
  #pragma unroll
  for(int c=0;c<5;++c){
    c1[c] = F1.c[c]; c2[c] = F2.c[c];
    #pragma unroll
    for(int d=0;d<5;++d){ A1[c][d]=F1.A[c][d]; A2[c][d]=F2.A[c][d]; }
  }
  #pragma unroll
  for(int k=0;k<25;++k) SWr[k] = skips_w[25*blk + k];
  #pragma unroll
  for(int k=0;k<5;++k)  SBr[k] = skips_b[5*blk + k];
  float acc[20];
  #pragma unroll
  for(int k=0;k<20;++k) acc[k]=0.f;
  const int gid = blockIdx.x*NTHR + threadIdx.x;
  for(int t=gid; t<M4Q; t+=TOTT){
    float4 z[5], h[5], zn[5];
    #pragma unroll
    for(int c=0;c<5;++c) z[c] = ((const float4*)(zbuf + (size_t)c*NROWS))[t];
    #pragma unroll
    for(int c=0;c<5;++c){
      float4 u = mk4(c1[c]);
      #pragma unroll
      for(int d=0;d<5;++d) u = fma44(A1[c][d], z[d], u);
      h[c] = relu4(u);
    }
    #pragma unroll
    for(int c=0;c<5;++c){
      float4 u = mk4(c2[c] + SBr[c]);
      #pragma unroll
      for(int d=0;d<5;++d){
        u = fma44(A2[c][d], h[d], u);
        u = fma44(SWr[c*5+d], z[d], u);
      }
      zn[c] = relu4(u);
    }
    #pragma unroll
    for(int c=0;c<5;++c) ((float4*)(zbuf + (size_t)c*NROWS))[t] = zn[c];
    acc_stats(zn, acc);
  }
  reduce_atomic(acc, stats + 32*(2*blk+2));
}

__global__ __launch_bounds__(NTHR)
void k_final(const float* __restrict__ zbuf, const float* __restrict__ stats,
             const float* __restrict__ lin9_w, const float* __restrict__ bn9_g,
             const float* __restrict__ bn9_b, const float* __restrict__ lin10_w,
             const float* __restrict__ lin10_b, float* __restrict__ out){
  __shared__ float A9s[2][5], c9s[2];
  if(threadIdx.x < 2)
    fold_generic(stats + 32*8, lin9_w, bn9_g, bn9_b, (int)threadIdx.x,
                 &A9s[threadIdx.x][0], &c9s[threadIdx.x]);
  __syncthreads();
  float A9[2][5], c9[2];
  #pragma unroll
  for(int c=0;c<2;++c){
    c9[c] = c9s[c];
    #pragma unroll
    for(int d=0;d<5;++d) A9[c][d] = A9s[c][d];
  }
  const float w10a = lin10_w[0], w10b = lin10_w[1], b10 = lin10_b[0];
  const int gid = blockIdx.x*NTHR + threadIdx.x;
  for(int t=gid; t<M4Q; t+=TOTT){
    float4 z[5];
    #pragma unroll
    for(int c=0;c<5;++c) z[c] = ((const float4*)(zbuf + (size_t)c*NROWS))[t];
    float4 u0 = mk4(c9[0]), u1 = mk4(c9[1]);
    #pragma unroll
    for(int d=0;d<5;++d){ u0 = fma44(A9[0][d], z[d], u0); u1 = fma44(A9[1][d], z[d], u1); }
    u0 = relu4(u0); u1 = relu4(u1);
    float4 o = mk4(b10);
    o = fma44(w10a, u0, o);
    o = fma44(w10b, u1, o);
    ((float4*)out)[t] = o;
  }
}

// ---------------- fallback path: recompute from x (tiny ws) ----------------

__global__ __launch_bounds__(NTHR)
void k_fromx(const float* __restrict__ x, float* __restrict__ stats,
             const float* __restrict__ lins_w, const float* __restrict__ bn_g,
             const float* __restrict__ bn_b, const float* __restrict__ skips_w,
             const float* __restrict__ skips_b, const float* __restrict__ lin9_w,
             const float* __restrict__ bn9_g, const float* __restrict__ bn9_b,
             const float* __restrict__ lin10_w, const float* __restrict__ lin10_b,
             float* __restrict__ out, int target, int do_final){
  __shared__ FoldLDS F[8];
  __shared__ float SW[100], SB[20];
  __shared__ float A9s[2][5], c9s[2];
  const int nf = do_final ? 8 : target;
  for(int L=0; L<nf; ++L)
    fold_layer(stats + 32*L, lins_w + 25*L, bn_g + 5*L, bn_b + 5*L, &F[L]);
  if(threadIdx.x < 100) SW[threadIdx.x] = skips_w[threadIdx.x];
  else if(threadIdx.x < 120) SB[threadIdx.x-100] = skips_b[threadIdx.x-100];
  if(do_final && threadIdx.x < 2)
    fold_generic(stats + 32*8, lin9_w, bn9_g, bn9_b, (int)threadIdx.x,
                 &A9s[threadIdx.x][0], &c9s[threadIdx.x]);
  __syncthreads();
  float w10a=0.f, w10b=0.f, b10=0.f;
  if(do_final){ w10a = lin10_w[0]; w10b = lin10_w[1]; b10 = lin10_b[0]; }
  float acc[20];
  #pragma unroll
  for(int k=0;k<20;++k) acc[k]=0.f;
  const int gid = blockIdx.x*NTHR + threadIdx.x;
  const int steps = do_final ? 8 : target;
  for(int t=gid; t<M4Q; t+=TOTT){
    union { float4 v[5]; float f[20]; } u;
    const float4* xp = (const float4*)(x + (size_t)t*20);
    #pragma unroll
    for(int q=0;q<5;++q) u.v[q] = xp[q];
    float4 z[5], h[5];
    #pragma unroll
    for(int c=0;c<5;++c) z[c] = make_float4(u.f[c], u.f[5+c], u.f[10+c], u.f[15+c]);
    #pragma unroll 1
    for(int s=1; s<=steps; ++s){
      const int L = s-1, b = (s-1)>>1;
      if(s & 1){
        #pragma unroll
        for(int c=0;c<5;++c){
          float4 t2 = mk4(F[L].c[c]);
          #pragma unroll
          for(int d=0;d<5;++d) t2 = fma44(F[L].A[c][d], z[d], t2);
          h[c] = relu4(t2);
        }
      } else {
        float4 zn[5];
        #pragma unroll
        for(int c=0;c<5;++c){
          float4 t2 = mk4(F[L].c[c] + SB[b*5+c]);
          #pragma unroll
          for(int d=0;d<5;++d){
            t2 = fma44(F[L].A[c][d], h[d], t2);
            t2 = fma44(SW[b*25+c*5+d], z[d], t2);
          }
          zn[c] = relu4(t2);
        }
        #pragma unroll
        for(int c=0;c<5;++c) z[c] = zn[c];
      }
    }
    if(do_final){
      float4 u0 = mk4(c9s[0]), u1 = mk4(c9s[1]);
      #pragma unroll
      for(int d=0;d<5;++d){ u0 = fma44(A9s[0][d], z[d], u0); u1 = fma44(A9s[1][d], z[d], u1); }
      u0 = relu4(u0); u1 = relu4(u1);
      float4 o = mk4(b10);
      o = fma44(w10a, u0, o);
      o = fma44(w10b, u1, o);
      ((float4*)out)[t] = o;
    } else {
      if(steps & 1) acc_stats(h, acc);
      else          acc_stats(z, acc);
    }
  }
  if(!do_final) reduce_atomic(acc, stats + 32*target);
}

extern "C" void kernel_launch(void* const* d_in, const int* in_sizes, int n_in,
                              void* d_out, int out_size, void* d_ws, size_t ws_size,
                              hipStream_t stream){
  (void)in_sizes; (void)n_in; (void)out_size;
  const float* x       = (const float*)d_in[0];
  const float* lins_w  = (const float*)d_in[1];
  // d_in[2] = lins_b: cancels inside BN, unused
  const float* skips_w = (const float*)d_in[3];
  const float* skips_b = (const float*)d_in[4];
  const float* bn_g    = (const float*)d_in[5];
  const float* bn_b    = (const float*)d_in[6];
  const float* lin9_w  = (const float*)d_in[7];
  // d_in[8] = lin9_b: cancels inside BN, unused
  const float* bn9_g   = (const float*)d_in[9];
  const float* bn9_b   = (const float*)d_in[10];
  const float* lin10_w = (const float*)d_in[11];
  const float* lin10_b = (const float*)d_in[12];
  float* out = (float*)d_out;

  const size_t zbytes = (size_t)5*NROWS*sizeof(float);
  if(ws_size >= zbytes + 4096){
    float* zbuf  = (float*)d_ws;
    float* stats = (float*)((char*)d_ws + zbytes);
    hipMemsetAsync(stats, 0, 9*32*sizeof(float), stream);
    k_transpose_stats<<<NBLK, NTHR, 0, stream>>>(x, zbuf, stats);
    for(int b=0;b<4;++b){
      k_stats_h<<<NBLK, NTHR, 0, stream>>>(zbuf, stats, lins_w, bn_g, bn_b, b);
      k_update_z<<<NBLK, NTHR, 0, stream>>>(zbuf, stats, lins_w, bn_g, bn_b,
                                            skips_w, skips_b, b);
    }
    k_final<<<NBLK, NTHR, 0, stream>>>(zbuf, stats, lin9_w, bn9_g, bn9_b,
                                       lin10_w, lin10_b, out);
  } else {
    float* stats = (float*)d_ws;
    hipMemsetAsync(stats, 0, 9*32*sizeof(float), stream);
    for(int s=0; s<=8; ++s)
      k_fromx<<<NBLK, NTHR, 0, stream>>>(x, stats, lins_w, bn_g, bn_b, skips_w,
                                         skips_b, lin9_w, bn9_g, bn9_b, lin10_w,
                                         lin10_b, out, s, 0);
    k_fromx<<<NBLK, NTHR, 0, stream>>>(x, stats, lins_w, bn_g, bn_b, skips_w,
                                       skips_b, lin9_w, bn9_g, bn9_b, lin10_w,
                                       lin10_b, out, 8, 1);
  }
}

// Round 2
// 424.249 us; speedup vs baseline: 1.0025x; 1.0025x over previous
//
#include <hip/hip_runtime.h>
#include <hip/hip_cooperative_groups.h>
#include <math.h>

namespace cg = cooperative_groups;

#define NROWS 4194304
#define M4Q   (NROWS/4)
#define EPSV  1e-5f
#define NBLK  1024
#define NTHR  256
#define TOTT  (NBLK*NTHR)

// Cooperative path config: 512 blocks x 256 thr = 131072 threads, 2 blocks/CU.
#define CBLK  512
#define CTHR  256
#define CTOT  (CBLK*CTHR)
#define GPT   (M4Q/CTOT)        // 8 float4-groups (32 rows) per thread
#define PSLOTS 64               // partial-reduction slots (8-way atomic contention)
#define PSTRIDE (PSLOTS*32)     // floats per stage region
#define PART_BYTES (9*PSTRIDE*4)

// Stage numbering: 0:x 1:h1 2:z1 3:h2 4:z2 5:h3 6:z3 7:h4 8:z4
// Stats: 20 floats/stage = 5 sums + 15 upper-tri second moments.
// Linear bias cancels inside BN (mean-subtracted), so lins_b/lin9_b unused.

struct FoldLDS { float A[5][5]; float c[5]; };

__device__ inline float4 mk4(float v){ return make_float4(v,v,v,v); }
__device__ inline float4 fma44(float a, const float4& b, const float4& c){
  return make_float4(fmaf(a,b.x,c.x), fmaf(a,b.y,c.y), fmaf(a,b.z,c.z), fmaf(a,b.w,c.w));
}
__device__ inline float4 relu4(const float4& a){
  return make_float4(fmaxf(a.x,0.f),fmaxf(a.y,0.f),fmaxf(a.z,0.f),fmaxf(a.w,0.f));
}

__device__ inline void acc_stats(const float4 z[5], float acc[20]){
  #pragma unroll
  for(int d=0; d<5; ++d) acc[d] += (z[d].x + z[d].y) + (z[d].z + z[d].w);
  int k = 5;
  #pragma unroll
  for(int d=0; d<5; ++d){
    #pragma unroll
    for(int e=d; e<5; ++e){
      acc[k] += z[d].x*z[e].x + z[d].y*z[e].y + z[d].z*z[e].z + z[d].w*z[e].w;
      ++k;
    }
  }
}

// Fold BN(Lin(z)) into affine y = A z + c from raw sums of z.
__device__ inline void fold_generic(const float* __restrict__ sums,
                                    const float* __restrict__ W,
                                    const float* __restrict__ g,
                                    const float* __restrict__ be,
                                    int c, float* Arow, float* cout){
  const float invN = 1.0f/(float)NROWS;
  float mu[5];
  #pragma unroll
  for(int d=0;d<5;++d) mu[d] = sums[d]*invN;
  float wr[5];
  #pragma unroll
  for(int d=0;d<5;++d) wr[d] = W[c*5+d];
  float m = 0.f, v = 0.f;
  #pragma unroll
  for(int d=0;d<5;++d){
    m += wr[d]*mu[d];
    #pragma unroll
    for(int e=0;e<5;++e){
      const int dd = d<e?d:e, ee = d<e?e:d;
      const float cov = sums[5 + dd*5+ee - (dd*(dd+1))/2]*invN - mu[d]*mu[e];
      v += wr[d]*wr[e]*cov;
    }
  }
  const float s = g[c] / sqrtf(v + EPSV);
  #pragma unroll
  for(int d=0;d<5;++d) Arow[d] = s*wr[d];
  *cout = be[c] - s*m;
}

// ======================= cooperative persistent kernel =======================

__device__ inline void block_reduce_partials(float acc[20], float* part_stage){
  #pragma unroll
  for(int k=0;k<20;++k){
    float v = acc[k];
    #pragma unroll
    for(int m=32;m>=1;m>>=1) v += __shfl_xor(v, m);
    acc[k] = v;
  }
  __shared__ float red[(CTHR/64)*20];
  const int lane = threadIdx.x & 63, wv = threadIdx.x >> 6;
  if(lane==0){
    #pragma unroll
    for(int k=0;k<20;++k) red[wv*20+k] = acc[k];
  }
  __syncthreads();
  if(threadIdx.x < 20){
    float s = 0.f;
    #pragma unroll
    for(int w=0; w<CTHR/64; ++w) s += red[w*20 + threadIdx.x];
    atomicAdd(part_stage + (blockIdx.x & (PSLOTS-1))*32 + threadIdx.x, s);
  }
  __syncthreads();   // red/raw reuse safety across stages
}

__device__ inline void sum_partials(const float* part_stage, float* raw){
  if(threadIdx.x < 20){
    float s = 0.f;
    #pragma unroll 8
    for(int j=0;j<PSLOTS;++j)
      s += __hip_atomic_load(part_stage + j*32 + (int)threadIdx.x,
                             __ATOMIC_RELAXED, __HIP_MEMORY_SCOPE_AGENT);
    raw[threadIdx.x] = s;
  }
  __syncthreads();
}

__global__ __launch_bounds__(CTHR, 2)
void k_coop(const float* __restrict__ x, float* __restrict__ part,
            const float* __restrict__ lins_w, const float* __restrict__ bn_g,
            const float* __restrict__ bn_b, const float* __restrict__ skips_w,
            const float* __restrict__ skips_b, const float* __restrict__ lin9_w,
            const float* __restrict__ bn9_g, const float* __restrict__ bn9_b,
            const float* __restrict__ lin10_w, const float* __restrict__ lin10_b,
            float* __restrict__ out){
  cg::grid_group grid = cg::this_grid();
  const int tid = blockIdx.x*CTHR + threadIdx.x;

  // Load 32 rows (8 float4-groups) into registers, SoA per group.
  float4 zz[GPT][5];
  #pragma unroll
  for(int g=0; g<GPT; ++g){
    const size_t G = (size_t)tid + (size_t)g*CTOT;
    union { float4 v[5]; float f[20]; } u;
    const float4* xp = (const float4*)(x + G*20);
    #pragma unroll
    for(int q=0;q<5;++q) u.v[q] = xp[q];
    #pragma unroll
    for(int c=0;c<5;++c) zz[g][c] = make_float4(u.f[c], u.f[5+c], u.f[10+c], u.f[15+c]);
  }

  float acc[20];
  #pragma unroll
  for(int k=0;k<20;++k) acc[k]=0.f;
  #pragma unroll
  for(int g=0; g<GPT; ++g) acc_stats(zz[g], acc);
  block_reduce_partials(acc, part + 0*PSTRIDE);
  __threadfence();
  grid.sync();

  __shared__ float raw[20];
  __shared__ FoldLDS F1, F2;
  __shared__ float SWs[25], SBs[5];

  #pragma unroll 1
  for(int b=0;b<4;++b){
    const int i=2*b, j=i+1;
    sum_partials(part + i*PSTRIDE, raw);
    if(threadIdx.x < 5)
      fold_generic(raw, lins_w+25*i, bn_g+5*i, bn_b+5*i, (int)threadIdx.x,
                   &F1.A[threadIdx.x][0], &F1.c[threadIdx.x]);
    if(threadIdx.x >= 64 && threadIdx.x < 89) SWs[threadIdx.x-64] = skips_w[25*b + threadIdx.x-64];
    if(threadIdx.x >= 96 && threadIdx.x < 101) SBs[threadIdx.x-96] = skips_b[5*b + threadIdx.x-96];
    __syncthreads();

    // pass A: stats of h = relu(F1 z)
    #pragma unroll
    for(int k=0;k<20;++k) acc[k]=0.f;
    #pragma unroll
    for(int g=0; g<GPT; ++g){
      float4 h[5];
      #pragma unroll
      for(int c=0;c<5;++c){
        float4 u = mk4(F1.c[c]);
        #pragma unroll
        for(int d=0;d<5;++d) u = fma44(F1.A[c][d], zz[g][d], u);
        h[c] = relu4(u);
      }
      acc_stats(h, acc);
    }
    block_reduce_partials(acc, part + j*PSTRIDE);
    __threadfence();
    grid.sync();

    sum_partials(part + j*PSTRIDE, raw);
    if(threadIdx.x < 5)
      fold_generic(raw, lins_w+25*j, bn_g+5*j, bn_b+5*j, (int)threadIdx.x,
                   &F2.A[threadIdx.x][0], &F2.c[threadIdx.x]);
    __syncthreads();

    // pass B: z' = relu(F2 h + SW z + (c2+SB)), stats of z'
    #pragma unroll
    for(int k=0;k<20;++k) acc[k]=0.f;
    #pragma unroll
    for(int g=0; g<GPT; ++g){
      float4 h[5];
      #pragma unroll
      for(int c=0;c<5;++c){
        float4 u = mk4(F1.c[c]);
        #pragma unroll
        for(int d=0;d<5;++d) u = fma44(F1.A[c][d], zz[g][d], u);
        h[c] = relu4(u);
      }
      float4 zn[5];
      #pragma unroll
      for(int c=0;c<5;++c){
        float4 u = mk4(F2.c[c] + SBs[c]);
        #pragma unroll
        for(int d=0;d<5;++d){
          u = fma44(F2.A[c][d], h[d], u);
          u = fma44(SWs[c*5+d], zz[g][d], u);
        }
        zn[c] = relu4(u);
      }
      #pragma unroll
      for(int c=0;c<5;++c) zz[g][c] = zn[c];
      acc_stats(zn, acc);
    }
    block_reduce_partials(acc, part + (i+2)*PSTRIDE);
    __threadfence();
    grid.sync();
  }

  // final: fold lin9+bn9, then lin10
  sum_partials(part + 8*PSTRIDE, raw);
  __shared__ float A9s[2][5], c9s[2];
  if(threadIdx.x < 2)
    fold_generic(raw, lin9_w, bn9_g, bn9_b, (int)threadIdx.x,
                 &A9s[threadIdx.x][0], &c9s[threadIdx.x]);
  __syncthreads();
  float A9[2][5], c9[2];
  #pragma unroll
  for(int c=0;c<2;++c){
    c9[c] = c9s[c];
    #pragma unroll
    for(int d=0;d<5;++d) A9[c][d] = A9s[c][d];
  }
  const float w10a = lin10_w[0], w10b = lin10_w[1], b10 = lin10_b[0];
  #pragma unroll
  for(int g=0; g<GPT; ++g){
    float4 u0 = mk4(c9[0]), u1 = mk4(c9[1]);
    #pragma unroll
    for(int d=0;d<5;++d){ u0 = fma44(A9[0][d], zz[g][d], u0); u1 = fma44(A9[1][d], zz[g][d], u1); }
    u0 = relu4(u0); u1 = relu4(u1);
    float4 o = mk4(b10);
    o = fma44(w10a, u0, o);
    o = fma44(w10b, u1, o);
    ((float4*)out)[(size_t)tid + (size_t)g*CTOT] = o;
  }
}

// ================== fallback multi-kernel path (round-1 code) ==================

__device__ inline void reduce_atomic(float acc[20], float* dst){
  #pragma unroll
  for(int k=0;k<20;++k){
    float v = acc[k];
    #pragma unroll
    for(int m=32;m>=1;m>>=1) v += __shfl_xor(v, m);
    acc[k] = v;
  }
  __shared__ float red[(NTHR/64)*20];
  const int lane = threadIdx.x & 63, wv = threadIdx.x >> 6;
  if(lane==0){
    #pragma unroll
    for(int k=0;k<20;++k) red[wv*20+k] = acc[k];
  }
  __syncthreads();
  if(threadIdx.x < 20){
    float s = 0.f;
    #pragma unroll
    for(int w=0; w<NTHR/64; ++w) s += red[w*20 + threadIdx.x];
    atomicAdd(dst + threadIdx.x, s);
  }
}

__device__ inline void fold_layer(const float* sums, const float* W,
                                  const float* g, const float* be, FoldLDS* F){
  if(threadIdx.x < 5)
    fold_generic(sums, W, g, be, (int)threadIdx.x,
                 &F->A[threadIdx.x][0], &F->c[threadIdx.x]);
}

__global__ __launch_bounds__(NTHR)
void k_transpose_stats(const float* __restrict__ x, float* __restrict__ zbuf,
                       float* __restrict__ stats){
  float acc[20];
  #pragma unroll
  for(int k=0;k<20;++k) acc[k]=0.f;
  const int gid = blockIdx.x*NTHR + threadIdx.x;
  for(int t=gid; t<M4Q; t+=TOTT){
    union { float4 v[5]; float f[20]; } u;
    const float4* xp = (const float4*)(x + (size_t)t*20);
    #pragma unroll
    for(int q=0;q<5;++q) u.v[q] = xp[q];
    float4 z[5];
    #pragma unroll
    for(int c=0;c<5;++c) z[c] = make_float4(u.f[c], u.f[5+c], u.f[10+c], u.f[15+c]);
    #pragma unroll
    for(int c=0;c<5;++c) ((float4*)(zbuf + (size_t)c*NROWS))[t] = z[c];
    acc_stats(z, acc);
  }
  reduce_atomic(acc, stats);
}

__global__ __launch_bounds__(NTHR)
void k_stats_h(const float* __restrict__ zbuf, float* __restrict__ stats,
               const float* __restrict__ lins_w, const float* __restrict__ bn_g,
               const float* __restrict__ bn_b, int blk){
  __shared__ FoldLDS F1;
  const int i = 2*blk;
  fold_layer(stats + 32*i, lins_w + 25*i, bn_g + 5*i, bn_b + 5*i, &F1);
  __syncthreads();
  float A1[5][5], c1[5];
  #pragma unroll
  for(int c=0;c<5;++c){
    c1[c] = F1.c[c];
    #pragma unroll
    for(int d=0;d<5;++d) A1[c][d] = F1.A[c][d];
  }
  float acc[20];
  #pragma unroll
  for(int k=0;k<20;++k) acc[k]=0.f;
  const int gid = blockIdx.x*NTHR + threadIdx.x;
  for(int t=gid; t<M4Q; t+=TOTT){
    float4 z[5], h[5];
    #pragma unroll
    for(int c=0;c<5;++c) z[c] = ((const float4*)(zbuf + (size_t)c*NROWS))[t];
    #pragma unroll
    for(int c=0;c<5;++c){
      float4 u = mk4(c1[c]);
      #pragma unroll
      for(int d=0;d<5;++d) u = fma44(A1[c][d], z[d], u);
      h[c] = relu4(u);
    }
    acc_stats(h, acc);
  }
  reduce_atomic(acc, stats + 32*(2*blk+1));
}

__global__ __launch_bounds__(NTHR)
void k_update_z(float* __restrict__ zbuf, float* __restrict__ stats,
                const float* __restrict__ lins_w, const float* __restrict__ bn_g,
                const float* __restrict__ bn_b, const float* __restrict__ skips_w,
                const float* __restrict__ skips_b, int blk){
  __shared__ FoldLDS F1, F2;
  const int i = 2*blk, j = 2*blk+1;
  fold_layer(stats + 32*i, lins_w + 25*i, bn_g + 5*i, bn_b + 5*i, &F1);
  fold_layer(stats + 32*j, lins_w + 25*j, bn_g + 5*j, bn_b + 5*j, &F2);
  __syncthreads();
  float A1[5][5], c1[5], A2[5][5], c2[5], SWr[25], SBr[5];
  #pragma unroll
  for(int c=0;c<5;++c){
    c1[c] = F1.c[c]; c2[c] = F2.c[c];
    #pragma unroll
    for(int d=0;d<5;++d){ A1[c][d]=F1.A[c][d]; A2[c][d]=F2.A[c][d]; }
  }
  #pragma unroll
  for(int k=0;k<25;++k) SWr[k] = skips_w[25*blk + k];
  #pragma unroll
  for(int k=0;k<5;++k)  SBr[k] = skips_b[5*blk + k];
  float acc[20];
  #pragma unroll
  for(int k=0;k<20;++k) acc[k]=0.f;
  const int gid = blockIdx.x*NTHR + threadIdx.x;
  for(int t=gid; t<M4Q; t+=TOTT){
    float4 z[5], h[5], zn[5];
    #pragma unroll
    for(int c=0;c<5;++c) z[c] = ((const float4*)(zbuf + (size_t)c*NROWS))[t];
    #pragma unroll
    for(int c=0;c<5;++c){
      float4 u = mk4(c1[c]);
      #pragma unroll
      for(int d=0;d<5;++d) u = fma44(A1[c][d], z[d], u);
      h[c] = relu4(u);
    }
    #pragma unroll
    for(int c=0;c<5;++c){
      float4 u = mk4(c2[c] + SBr[c]);
      #pragma unroll
      for(int d=0;d<5;++d){
        u = fma44(A2[c][d], h[d], u);
        u = fma44(SWr[c*5+d], z[d], u);
      }
      zn[c] = relu4(u);
    }
    #pragma unroll
    for(int c=0;c<5;++c) ((float4*)(zbuf + (size_t)c*NROWS))[t] = zn[c];
    acc_stats(zn, acc);
  }
  reduce_atomic(acc, stats + 32*(2*blk+2));
}

__global__ __launch_bounds__(NTHR)
void k_final(const float* __restrict__ zbuf, const float* __restrict__ stats,
             const float* __restrict__ lin9_w, const float* __restrict__ bn9_g,
             const float* __restrict__ bn9_b, const float* __restrict__ lin10_w,
             const float* __restrict__ lin10_b, float* __restrict__ out){
  __shared__ float A9s[2][5], c9s[2];
  if(threadIdx.x < 2)
    fold_generic(stats + 32*8, lin9_w, bn9_g, bn9_b, (int)threadIdx.x,
                 &A9s[threadIdx.x][0], &c9s[threadIdx.x]);
  __syncthreads();
  float A9[2][5], c9[2];
  #pragma unroll
  for(int c=0;c<2;++c){
    c9[c] = c9s[c];
    #pragma unroll
    for(int d=0;d<5;++d) A9[c][d] = A9s[c][d];
  }
  const float w10a = lin10_w[0], w10b = lin10_w[1], b10 = lin10_b[0];
  const int gid = blockIdx.x*NTHR + threadIdx.x;
  for(int t=gid; t<M4Q; t+=TOTT){
    float4 z[5];
    #pragma unroll
    for(int c=0;c<5;++c) z[c] = ((const float4*)(zbuf + (size_t)c*NROWS))[t];
    float4 u0 = mk4(c9[0]), u1 = mk4(c9[1]);
    #pragma unroll
    for(int d=0;d<5;++d){ u0 = fma44(A9[0][d], z[d], u0); u1 = fma44(A9[1][d], z[d], u1); }
    u0 = relu4(u0); u1 = relu4(u1);
    float4 o = mk4(b10);
    o = fma44(w10a, u0, o);
    o = fma44(w10b, u1, o);
    ((float4*)out)[t] = o;
  }
}

__global__ __launch_bounds__(NTHR)
void k_fromx(const float* __restrict__ x, float* __restrict__ stats,
             const float* __restrict__ lins_w, const float* __restrict__ bn_g,
             const float* __restrict__ bn_b, const float* __restrict__ skips_w,
             const float* __restrict__ skips_b, const float* __restrict__ lin9_w,
             const float* __restrict__ bn9_g, const float* __restrict__ bn9_b,
             const float* __restrict__ lin10_w, const float* __restrict__ lin10_b,
             float* __restrict__ out, int target, int do_final){
  __shared__ FoldLDS F[8];
  __shared__ float SW[100], SB[20];
  __shared__ float A9s[2][5], c9s[2];
  const int nf = do_final ? 8 : target;
  for(int L=0; L<nf; ++L)
    fold_layer(stats + 32*L, lins_w + 25*L, bn_g + 5*L, bn_b + 5*L, &F[L]);
  if(threadIdx.x < 100) SW[threadIdx.x] = skips_w[threadIdx.x];
  else if(threadIdx.x < 120) SB[threadIdx.x-100] = skips_b[threadIdx.x-100];
  if(do_final && threadIdx.x < 2)
    fold_generic(stats + 32*8, lin9_w, bn9_g, bn9_b, (int)threadIdx.x,
                 &A9s[threadIdx.x][0], &c9s[threadIdx.x]);
  __syncthreads();
  float w10a=0.f, w10b=0.f, b10=0.f;
  if(do_final){ w10a = lin10_w[0]; w10b = lin10_w[1]; b10 = lin10_b[0]; }
  float acc[20];
  #pragma unroll
  for(int k=0;k<20;++k) acc[k]=0.f;
  const int gid = blockIdx.x*NTHR + threadIdx.x;
  const int steps = do_final ? 8 : target;
  for(int t=gid; t<M4Q; t+=TOTT){
    union { float4 v[5]; float f[20]; } u;
    const float4* xp = (const float4*)(x + (size_t)t*20);
    #pragma unroll
    for(int q=0;q<5;++q) u.v[q] = xp[q];
    float4 z[5], h[5];
    #pragma unroll
    for(int c=0;c<5;++c) z[c] = make_float4(u.f[c], u.f[5+c], u.f[10+c], u.f[15+c]);
    #pragma unroll 1
    for(int s=1; s<=steps; ++s){
      const int L = s-1, b = (s-1)>>1;
      if(s & 1){
        #pragma unroll
        for(int c=0;c<5;++c){
          float4 t2 = mk4(F[L].c[c]);
          #pragma unroll
          for(int d=0;d<5;++d) t2 = fma44(F[L].A[c][d], z[d], t2);
          h[c] = relu4(t2);
        }
      } else {
        float4 zn[5];
        #pragma unroll
        for(int c=0;c<5;++c){
          float4 t2 = mk4(F[L].c[c] + SB[b*5+c]);
          #pragma unroll
          for(int d=0;d<5;++d){
            t2 = fma44(F[L].A[c][d], h[d], t2);
            t2 = fma44(SW[b*25+c*5+d], z[d], t2);
          }
          zn[c] = relu4(t2);
        }
        #pragma unroll
        for(int c=0;c<5;++c) z[c] = zn[c];
      }
    }
    if(do_final){
      float4 u0 = mk4(c9s[0]), u1 = mk4(c9s[1]);
      #pragma unroll
      for(int d=0;d<5;++d){ u0 = fma44(A9s[0][d], z[d], u0); u1 = fma44(A9s[1][d], z[d], u1); }
      u0 = relu4(u0); u1 = relu4(u1);
      float4 o = mk4(b10);
      o = fma44(w10a, u0, o);
      o = fma44(w10b, u1, o);
      ((float4*)out)[t] = o;
    } else {
      if(steps & 1) acc_stats(h, acc);
      else          acc_stats(z, acc);
    }
  }
  if(!do_final) reduce_atomic(acc, stats + 32*target);
}

extern "C" void kernel_launch(void* const* d_in, const int* in_sizes, int n_in,
                              void* d_out, int out_size, void* d_ws, size_t ws_size,
                              hipStream_t stream){
  (void)in_sizes; (void)n_in; (void)out_size;
  const float* x       = (const float*)d_in[0];
  const float* lins_w  = (const float*)d_in[1];
  // d_in[2] = lins_b: cancels inside BN, unused
  const float* skips_w = (const float*)d_in[3];
  const float* skips_b = (const float*)d_in[4];
  const float* bn_g    = (const float*)d_in[5];
  const float* bn_b    = (const float*)d_in[6];
  const float* lin9_w  = (const float*)d_in[7];
  // d_in[8] = lin9_b: cancels inside BN, unused
  const float* bn9_g   = (const float*)d_in[9];
  const float* bn9_b   = (const float*)d_in[10];
  const float* lin10_w = (const float*)d_in[11];
  const float* lin10_b = (const float*)d_in[12];
  float* out = (float*)d_out;

  // Decide cooperative path (pure host queries — identical every call).
  int dev = 0; hipGetDevice(&dev);
  int coop = 0; hipDeviceGetAttribute(&coop, hipDeviceAttributeCooperativeLaunch, dev);
  int ncu = 0;  hipDeviceGetAttribute(&ncu, hipDeviceAttributeMultiprocessorCount, dev);
  int nb = 0;   hipOccupancyMaxActiveBlocksPerMultiprocessor(&nb, k_coop, CTHR, 0);
  const bool use_coop = coop && nb > 0 && ncu > 0 &&
                        (long long)nb * ncu >= CBLK && ws_size >= (size_t)PART_BYTES;

  if(use_coop){
    float* part = (float*)d_ws;
    hipMemsetAsync(part, 0, PART_BYTES, stream);
    void* args[13];
    args[0]=(void*)&x;       args[1]=(void*)&part;    args[2]=(void*)&lins_w;
    args[3]=(void*)&bn_g;    args[4]=(void*)&bn_b;    args[5]=(void*)&skips_w;
    args[6]=(void*)&skips_b; args[7]=(void*)&lin9_w;  args[8]=(void*)&bn9_g;
    args[9]=(void*)&bn9_b;   args[10]=(void*)&lin10_w; args[11]=(void*)&lin10_b;
    args[12]=(void*)&out;
    hipLaunchCooperativeKernel((void*)k_coop, dim3(CBLK), dim3(CTHR), args, 0, stream);
    return;
  }

  const size_t zbytes = (size_t)5*NROWS*sizeof(float);
  if(ws_size >= zbytes + 4096){
    float* zbuf  = (float*)d_ws;
    float* stats = (float*)((char*)d_ws + zbytes);
    hipMemsetAsync(stats, 0, 9*32*sizeof(float), stream);
    k_transpose_stats<<<NBLK, NTHR, 0, stream>>>(x, zbuf, stats);
    for(int b=0;b<4;++b){
      k_stats_h<<<NBLK, NTHR, 0, stream>>>(zbuf, stats, lins_w, bn_g, bn_b, b);
      k_update_z<<<NBLK, NTHR, 0, stream>>>(zbuf, stats, lins_w, bn_g, bn_b,
                                            skips_w, skips_b, b);
    }
    k_final<<<NBLK, NTHR, 0, stream>>>(zbuf, stats, lin9_w, bn9_g, bn9_b,
                                       lin10_w, lin10_b, out);
  } else {
    float* stats = (float*)d_ws;
    hipMemsetAsync(stats, 0, 9*32*sizeof(float), stream);
    for(int s=0; s<=8; ++s)
      k_fromx<<<NBLK, NTHR, 0, stream>>>(x, stats, lins_w, bn_g, bn_b, skips_w,
                                         skips_b, lin9_w, bn9_g, bn9_b, lin10_w,
                                         lin10_b, out, s, 0);
    k_fromx<<<NBLK, NTHR, 0, stream>>>(x, stats, lins_w, bn_g, bn_b, skips_w,
                                       skips_b, lin9_w, bn9_g, bn9_b, lin10_w,
                                       lin10_b, out, 8, 1);
  }
}